// Round 4
// baseline (5878.746 us; speedup 1.0000x reference)
//
#include <hip/hip_runtime.h>
#include <hip/hip_fp16.h>
#include <hip/hip_bf16.h>

#define DM   256      // d_model
#define DI   512      // d_inner
#define TG   768      // 3*d_model
#define TSEQ 4096
#define NB   8
#define MTOT (NB*TSEQ) // 32768

typedef _Float16 h2f __attribute__((ext_vector_type(2)));
typedef _Float16 h8f __attribute__((ext_vector_type(8)));

// ---------------- Phase 1: tiled fp32 GEMM, C = act(A @ W^T + bias) in fp16 ----
template<bool A_HALF, bool GELU_ACT>
__global__ __launch_bounds__(256) void gemm_bias(
    const void* __restrict__ Ap, const float* __restrict__ W,
    const float* __restrict__ bias, __half* __restrict__ C,
    int M, int N, int K)
{
  __shared__ float As[16][132];   // transposed: [k][m]
  __shared__ float Ws[16][132];   // transposed: [k][n]
  const int tid = threadIdx.x;
  const int tx = tid & 15, ty = tid >> 4;
  const int m0 = blockIdx.y * 128;
  const int n0 = blockIdx.x * 128;

  float acc[8][8] = {};

  for (int k0 = 0; k0 < K; k0 += 16) {
    if constexpr (A_HALF) {
      const __half* A = (const __half*)Ap;
      int r = tid >> 1, seg = (tid & 1) * 8;
      float4 raw = *(const float4*)(A + (size_t)(m0 + r) * K + k0 + seg);
      const __half* hv = (const __half*)&raw;
      #pragma unroll
      for (int q = 0; q < 8; q++) As[seg + q][r] = __half2float(hv[q]);
    } else {
      const float* A = (const float*)Ap;
      #pragma unroll
      for (int rep = 0; rep < 2; rep++) {
        int r = (tid >> 2) + rep * 64;
        int seg = (tid & 3) * 4;
        float4 v = *(const float4*)(A + (size_t)(m0 + r) * K + k0 + seg);
        As[seg + 0][r] = v.x; As[seg + 1][r] = v.y;
        As[seg + 2][r] = v.z; As[seg + 3][r] = v.w;
      }
    }
    #pragma unroll
    for (int rep = 0; rep < 2; rep++) {
      int r = (tid >> 2) + rep * 64;
      int seg = (tid & 3) * 4;
      float4 v = *(const float4*)(W + (size_t)(n0 + r) * K + k0 + seg);
      Ws[seg + 0][r] = v.x; Ws[seg + 1][r] = v.y;
      Ws[seg + 2][r] = v.z; Ws[seg + 3][r] = v.w;
    }
    __syncthreads();
    #pragma unroll
    for (int kk = 0; kk < 16; ++kk) {
      float a[8], b[8];
      *(float4*)&a[0] = *(const float4*)&As[kk][ty * 8];
      *(float4*)&a[4] = *(const float4*)&As[kk][ty * 8 + 4];
      *(float4*)&b[0] = *(const float4*)&Ws[kk][tx * 8];
      *(float4*)&b[4] = *(const float4*)&Ws[kk][tx * 8 + 4];
      #pragma unroll
      for (int i = 0; i < 8; i++)
        #pragma unroll
        for (int j = 0; j < 8; j++)
          acc[i][j] += a[i] * b[j];
    }
    __syncthreads();
  }

  #pragma unroll
  for (int i = 0; i < 8; i++) {
    int m = m0 + ty * 8 + i;
    #pragma unroll
    for (int j = 0; j < 8; j++) {
      int n = n0 + tx * 8 + j;
      float v = acc[i][j] + bias[n];
      if constexpr (GELU_ACT) {
        v = 0.5f * v * (1.0f + erff(v * 0.70710678118654752f));  // exact GELU
      }
      C[(size_t)m * N + n] = __float2half(v);
    }
  }
}

// ---------------- DPP pair butterfly (lane 2u <-> 2u+1), VALU only -----------
__device__ __forceinline__ float dpp_xor1_add(float v) {
  int i = __builtin_bit_cast(int, v);
  int s = __builtin_amdgcn_update_dpp(i, i, 0xB1, 0xF, 0xF, true); // quad_perm [1,0,3,2]
  return v + __builtin_bit_cast(float, s);
}

// ---------------- Phase 2: persistent GRU scan, one block per batch ----------
// 512 threads = 8 waves = 2 waves/SIMD -> VGPR cap 512/2 = 256 (round-3 lesson:
// at 768 thr the cap was 168 = exactly the need, so RA left w[] in scratch;
// VGPR_Count=84 is the spill signature).
// Lane pair (2u,2u+1) owns hidden unit u: lane p holds K-half p of the three
// gate rows {u, 256+u, 512+u} = 192 h2f regs. After a 1-instr DPP butterfly
// both lanes have full r/z/n h-side sums -> no gsig LDS exchange, and with a
// double-buffered h state only ONE barrier per timestep.
__global__ __launch_bounds__(512, 2) void gru_scan(
    const __half* __restrict__ gx,   // [B, T, 768] fp16 (includes b_ih)
    const float*  __restrict__ Whh,  // [768, 256]
    const float*  __restrict__ bhh,  // [768]
    float* __restrict__ out)         // [B, T, 256]
{
  const int b = blockIdx.x;
  const int j = threadIdx.x;   // 0..511
  const int u = j >> 1;        // hidden unit 0..255
  const int p = j & 1;         // K-half

  __shared__ __align__(16) _Float16 hbuf[2][DM];  // double-buffered state (f16)

  // ---- load weights: 3 rows x 128 cols (this lane's K-half) as 192 h2f ----
  h2f wr[64], wz[64], wn[64];
  {
    const float* rr = Whh + (size_t)u * DM + p * 128;
    const float* rz = rr + (size_t)DM * DM;
    const float* rn = rz + (size_t)DM * DM;
    #pragma unroll
    for (int i = 0; i < 32; ++i) {
      float4 f = *(const float4*)(rr + 4 * i);
      h2f t0; t0[0] = (_Float16)f.x; t0[1] = (_Float16)f.y;
      h2f t1; t1[0] = (_Float16)f.z; t1[1] = (_Float16)f.w;
      wr[2 * i] = t0; wr[2 * i + 1] = t1;
      if (i & 1) __builtin_amdgcn_sched_barrier(0);
    }
    #pragma unroll
    for (int i = 0; i < 32; ++i) {
      float4 f = *(const float4*)(rz + 4 * i);
      h2f t0; t0[0] = (_Float16)f.x; t0[1] = (_Float16)f.y;
      h2f t1; t1[0] = (_Float16)f.z; t1[1] = (_Float16)f.w;
      wz[2 * i] = t0; wz[2 * i + 1] = t1;
      if (i & 1) __builtin_amdgcn_sched_barrier(0);
    }
    #pragma unroll
    for (int i = 0; i < 32; ++i) {
      float4 f = *(const float4*)(rn + 4 * i);
      h2f t0; t0[0] = (_Float16)f.x; t0[1] = (_Float16)f.y;
      h2f t1; t1[0] = (_Float16)f.z; t1[1] = (_Float16)f.w;
      wn[2 * i] = t0; wn[2 * i + 1] = t1;
      if (i & 1) __builtin_amdgcn_sched_barrier(0);
    }
  }
  const float br = bhh[u];
  const float bz = bhh[DM + u];
  const float bn = bhh[2 * DM + u];
  float hloc = 0.0f;           // previous h for unit u (both lanes track it)

  if (j < DM) hbuf[0][j] = (_Float16)0.0f;
  __syncthreads();

  const __half* gp = gx + (size_t)b * TSEQ * TG;
  float* outb = out + (size_t)b * TSEQ * DM;

  float gxr = __half2float(gp[u]);
  float gxz = __half2float(gp[DM + u]);
  float gxn = __half2float(gp[2 * DM + u]);

  for (int t = 0; t < TSEQ; ++t) {
    const int cur = t & 1;
    const h8f* hp = (const h8f*)(&hbuf[cur][0]) + p * 16;  // this lane's 16 chunks

    // prefetch next timestep's gx (overlaps with the dot loop)
    float nr = 0.f, nz = 0.f, nn = 0.f;
    if (t + 1 < TSEQ) {
      const __half* g1 = gp + TG;
      nr = __half2float(g1[u]);
      nz = __half2float(g1[DM + u]);
      nn = __half2float(g1[2 * DM + u]);
    }

    // ---- partial dots over this lane's 128 columns ----
    float ar = 0.f, az = 0.f, an = 0.f;
    #pragma unroll
    for (int i = 0; i < 16; ++i) {
      union { h8f v; h2f c[4]; } hh;
      hh.v = hp[i];
      ar = __builtin_amdgcn_fdot2(wr[4 * i + 0], hh.c[0], ar, false);
      az = __builtin_amdgcn_fdot2(wz[4 * i + 0], hh.c[0], az, false);
      an = __builtin_amdgcn_fdot2(wn[4 * i + 0], hh.c[0], an, false);
      ar = __builtin_amdgcn_fdot2(wr[4 * i + 1], hh.c[1], ar, false);
      az = __builtin_amdgcn_fdot2(wz[4 * i + 1], hh.c[1], az, false);
      an = __builtin_amdgcn_fdot2(wn[4 * i + 1], hh.c[1], an, false);
      ar = __builtin_amdgcn_fdot2(wr[4 * i + 2], hh.c[2], ar, false);
      az = __builtin_amdgcn_fdot2(wz[4 * i + 2], hh.c[2], az, false);
      an = __builtin_amdgcn_fdot2(wn[4 * i + 2], hh.c[2], an, false);
      ar = __builtin_amdgcn_fdot2(wr[4 * i + 3], hh.c[3], ar, false);
      az = __builtin_amdgcn_fdot2(wz[4 * i + 3], hh.c[3], az, false);
      an = __builtin_amdgcn_fdot2(wn[4 * i + 3], hh.c[3], an, false);
      if (i & 1) __builtin_amdgcn_sched_barrier(0);   // cap lookahead: <=2 h8f live
    }
    // ---- pair butterfly: both lanes get the full 256-wide sums ----
    ar = dpp_xor1_add(ar);
    az = dpp_xor1_add(az);
    an = dpp_xor1_add(an);

    // ---- gates (redundantly on both lanes of the pair; no LDS exchange) ----
    float r = 1.0f / (1.0f + __expf(-(gxr + ar + br)));
    float z = 1.0f / (1.0f + __expf(-(gxz + az + bz)));
    float n = tanhf(gxn + r * (an + bn));
    float hnew = (1.0f - z) * n + z * hloc;
    hloc = hnew;

    if (p == 0) {
      hbuf[cur ^ 1][u] = (_Float16)hnew;
      outb[(size_t)t * DM + u] = hnew;
    }
    __syncthreads();   // single barrier: writes to buf^1 visible before next read

    gp += TG;
    gxr = nr; gxz = nz; gxn = nn;
  }
}

extern "C" void kernel_launch(void* const* d_in, const int* in_sizes, int n_in,
                              void* d_out, int out_size, void* d_ws, size_t ws_size,
                              hipStream_t stream) {
  const float* x   = (const float*)d_in[0];
  const float* W1  = (const float*)d_in[1];
  const float* b1  = (const float*)d_in[2];
  const float* Wih = (const float*)d_in[3];
  const float* bih = (const float*)d_in[4];
  const float* Whh = (const float*)d_in[5];
  const float* bhh = (const float*)d_in[6];
  float* out = (float*)d_out;

  char* ws = (char*)d_ws;
  __half* h  = (__half*)ws;                                   // [32768,512] fp16
  size_t h_bytes = (size_t)MTOT * DI * sizeof(__half);
  h_bytes = (h_bytes + 255) & ~(size_t)255;
  __half* gxbuf = (__half*)(ws + h_bytes);                    // [32768,768] fp16

  dim3 blk(256);
  gemm_bias<false, true><<<dim3(DI / 128, MTOT / 128), blk, 0, stream>>>(
      x, W1, b1, h, MTOT, DI, DM);
  gemm_bias<true, false><<<dim3(TG / 128, MTOT / 128), blk, 0, stream>>>(
      h, Wih, bih, gxbuf, MTOT, TG, DI);
  gru_scan<<<NB, 512, 0, stream>>>(gxbuf, Whh, bhh, out);
}

// Round 5
// 4944.588 us; speedup vs baseline: 1.1889x; 1.1889x over previous
//
#include <hip/hip_runtime.h>
#include <hip/hip_fp16.h>
#include <hip/hip_bf16.h>

#define DM   256      // d_model
#define DI   512      // d_inner
#define TG   768      // 3*d_model
#define TSEQ 4096
#define NB   8
#define MTOT (NB*TSEQ) // 32768

typedef _Float16 h2f __attribute__((ext_vector_type(2)));
typedef _Float16 h8f __attribute__((ext_vector_type(8)));

// ---------------- Phase 1: tiled fp32 GEMM, C = act(A @ W^T + bias) in fp16 ----
template<bool A_HALF, bool GELU_ACT>
__global__ __launch_bounds__(256) void gemm_bias(
    const void* __restrict__ Ap, const float* __restrict__ W,
    const float* __restrict__ bias, __half* __restrict__ C,
    int M, int N, int K)
{
  __shared__ float As[16][132];   // transposed: [k][m]
  __shared__ float Ws[16][132];   // transposed: [k][n]
  const int tid = threadIdx.x;
  const int tx = tid & 15, ty = tid >> 4;
  const int m0 = blockIdx.y * 128;
  const int n0 = blockIdx.x * 128;

  float acc[8][8] = {};

  for (int k0 = 0; k0 < K; k0 += 16) {
    if constexpr (A_HALF) {
      const __half* A = (const __half*)Ap;
      int r = tid >> 1, seg = (tid & 1) * 8;
      float4 raw = *(const float4*)(A + (size_t)(m0 + r) * K + k0 + seg);
      const __half* hv = (const __half*)&raw;
      #pragma unroll
      for (int q = 0; q < 8; q++) As[seg + q][r] = __half2float(hv[q]);
    } else {
      const float* A = (const float*)Ap;
      #pragma unroll
      for (int rep = 0; rep < 2; rep++) {
        int r = (tid >> 2) + rep * 64;
        int seg = (tid & 3) * 4;
        float4 v = *(const float4*)(A + (size_t)(m0 + r) * K + k0 + seg);
        As[seg + 0][r] = v.x; As[seg + 1][r] = v.y;
        As[seg + 2][r] = v.z; As[seg + 3][r] = v.w;
      }
    }
    #pragma unroll
    for (int rep = 0; rep < 2; rep++) {
      int r = (tid >> 2) + rep * 64;
      int seg = (tid & 3) * 4;
      float4 v = *(const float4*)(W + (size_t)(n0 + r) * K + k0 + seg);
      Ws[seg + 0][r] = v.x; Ws[seg + 1][r] = v.y;
      Ws[seg + 2][r] = v.z; Ws[seg + 3][r] = v.w;
    }
    __syncthreads();
    #pragma unroll
    for (int kk = 0; kk < 16; ++kk) {
      float a[8], b[8];
      *(float4*)&a[0] = *(const float4*)&As[kk][ty * 8];
      *(float4*)&a[4] = *(const float4*)&As[kk][ty * 8 + 4];
      *(float4*)&b[0] = *(const float4*)&Ws[kk][tx * 8];
      *(float4*)&b[4] = *(const float4*)&Ws[kk][tx * 8 + 4];
      #pragma unroll
      for (int i = 0; i < 8; i++)
        #pragma unroll
        for (int j = 0; j < 8; j++)
          acc[i][j] += a[i] * b[j];
    }
    __syncthreads();
  }

  #pragma unroll
  for (int i = 0; i < 8; i++) {
    int m = m0 + ty * 8 + i;
    #pragma unroll
    for (int j = 0; j < 8; j++) {
      int n = n0 + tx * 8 + j;
      float v = acc[i][j] + bias[n];
      if constexpr (GELU_ACT) {
        v = 0.5f * v * (1.0f + erff(v * 0.70710678118654752f));  // exact GELU
      }
      C[(size_t)m * N + n] = __float2half(v);
    }
  }
}

// ---------------- DPP pair butterfly (lane 2u <-> 2u+1), VALU only -----------
__device__ __forceinline__ float dpp_xor1_add(float v) {
  int i = __builtin_bit_cast(int, v);
  int s = __builtin_amdgcn_update_dpp(i, i, 0xB1, 0xF, 0xF, true); // quad_perm [1,0,3,2]
  return v + __builtin_bit_cast(float, s);
}

// ---------------- Phase 2: persistent GRU scan, one block per batch ----------
// ROUND-4 LESSON: __launch_bounds__ 2nd arg behaves as CUDA min-BLOCKS-per-CU:
// (512,2) -> 16 waves/CU -> 4 waves/SIMD -> VGPR budget 512/4 = 128 (observed
// VGPR_Count=128, weights spilled). (768,3) -> clamp 2 blocks -> 24 waves ->
// 512/6=85 (observed 84). Fix: (512,1) + amdgpu_waves_per_eu(2,2) -> budget 256.
// Lane pair (2u,2u+1) owns hidden unit u: lane p holds K-half p of the three
// gate rows {u, 256+u, 512+u} = 192 h2f regs; ~230 total < 256.
// h state double-buffered in LDS, split+padded per K-half (272B stride) so the
// pair's two broadcast addresses hit DIFFERENT bank groups (round-4 conflicts).
__global__ __launch_bounds__(512, 1) __attribute__((amdgpu_waves_per_eu(2, 2)))
void gru_scan(
    const __half* __restrict__ gx,   // [B, T, 768] fp16 (includes b_ih)
    const float*  __restrict__ Whh,  // [768, 256]
    const float*  __restrict__ bhh,  // [768]
    float* __restrict__ out)         // [B, T, 256]
{
  const int b = blockIdx.x;
  const int j = threadIdx.x;   // 0..511
  const int u = j >> 1;        // hidden unit 0..255
  const int p = j & 1;         // K-half

  // [buf][half][128 data + 8 pad]: half stride 272B -> bank offset 4 between
  // the two broadcast addresses of a pair -> conflict-free.
  __shared__ __align__(16) _Float16 hbuf[2][2][136];

  // ---- load weights: 3 rows x 128 cols (this lane's K-half) as 192 h2f ----
  h2f wr[64], wz[64], wn[64];
  {
    const float* rr = Whh + (size_t)u * DM + p * 128;
    const float* rz = rr + (size_t)DM * DM;
    const float* rn = rz + (size_t)DM * DM;
    #pragma unroll
    for (int i = 0; i < 32; ++i) {
      float4 f = *(const float4*)(rr + 4 * i);
      h2f t0; t0[0] = (_Float16)f.x; t0[1] = (_Float16)f.y;
      h2f t1; t1[0] = (_Float16)f.z; t1[1] = (_Float16)f.w;
      wr[2 * i] = t0; wr[2 * i + 1] = t1;
      if (i & 1) __builtin_amdgcn_sched_barrier(0);
    }
    #pragma unroll
    for (int i = 0; i < 32; ++i) {
      float4 f = *(const float4*)(rz + 4 * i);
      h2f t0; t0[0] = (_Float16)f.x; t0[1] = (_Float16)f.y;
      h2f t1; t1[0] = (_Float16)f.z; t1[1] = (_Float16)f.w;
      wz[2 * i] = t0; wz[2 * i + 1] = t1;
      if (i & 1) __builtin_amdgcn_sched_barrier(0);
    }
    #pragma unroll
    for (int i = 0; i < 32; ++i) {
      float4 f = *(const float4*)(rn + 4 * i);
      h2f t0; t0[0] = (_Float16)f.x; t0[1] = (_Float16)f.y;
      h2f t1; t1[0] = (_Float16)f.z; t1[1] = (_Float16)f.w;
      wn[2 * i] = t0; wn[2 * i + 1] = t1;
      if (i & 1) __builtin_amdgcn_sched_barrier(0);
    }
  }
  const float br = bhh[u];
  const float bz = bhh[DM + u];
  const float bn = bhh[2 * DM + u];
  float hloc = 0.0f;

  if (j < DM) hbuf[0][j >> 7][j & 127] = (_Float16)0.0f;
  __syncthreads();

  const __half* gp = gx + (size_t)b * TSEQ * TG;
  float* outb = out + (size_t)b * TSEQ * DM;

  float gxr = __half2float(gp[u]);
  float gxz = __half2float(gp[DM + u]);
  float gxn = __half2float(gp[2 * DM + u]);

  // 12 fdot2 on one 8-half chunk of h, weight base index B (compile-time)
  #define DOT8(vv, B) do {                                         \
    h2f c0 = __builtin_shufflevector(vv, vv, 0, 1);                \
    h2f c1 = __builtin_shufflevector(vv, vv, 2, 3);                \
    h2f c2 = __builtin_shufflevector(vv, vv, 4, 5);                \
    h2f c3 = __builtin_shufflevector(vv, vv, 6, 7);                \
    ar0 = __builtin_amdgcn_fdot2(wr[(B)+0], c0, ar0, false);       \
    az0 = __builtin_amdgcn_fdot2(wz[(B)+0], c0, az0, false);       \
    an0 = __builtin_amdgcn_fdot2(wn[(B)+0], c0, an0, false);       \
    ar1 = __builtin_amdgcn_fdot2(wr[(B)+1], c1, ar1, false);       \
    az1 = __builtin_amdgcn_fdot2(wz[(B)+1], c1, az1, false);       \
    an1 = __builtin_amdgcn_fdot2(wn[(B)+1], c1, an1, false);       \
    ar0 = __builtin_amdgcn_fdot2(wr[(B)+2], c2, ar0, false);       \
    az0 = __builtin_amdgcn_fdot2(wz[(B)+2], c2, az0, false);       \
    an0 = __builtin_amdgcn_fdot2(wn[(B)+2], c2, an0, false);       \
    ar1 = __builtin_amdgcn_fdot2(wr[(B)+3], c3, ar1, false);       \
    az1 = __builtin_amdgcn_fdot2(wz[(B)+3], c3, az1, false);       \
    an1 = __builtin_amdgcn_fdot2(wn[(B)+3], c3, an1, false);       \
  } while (0)

  for (int t = 0; t < TSEQ; ++t) {
    const int cur = t & 1;
    const h8f* hp = (const h8f*)(&hbuf[cur][p][0]);

    // prefetch next timestep's gx (hides under the dot loop)
    float nr = 0.f, nz = 0.f, nn = 0.f;
    if (t + 1 < TSEQ) {
      const __half* g1 = gp + TG;
      nr = __half2float(g1[u]);
      nz = __half2float(g1[DM + u]);
      nn = __half2float(g1[2 * DM + u]);
    }

    // ---- partial dots, 2-stage rolling chunk buffer (<=2 h8f live) ----
    float ar0 = 0.f, ar1 = 0.f, az0 = 0.f, az1 = 0.f, an0 = 0.f, an1 = 0.f;
    h8f v0 = hp[0], v1;
    #pragma unroll
    for (int i = 0; i < 16; i += 2) {
      v1 = hp[i + 1];
      DOT8(v0, 4 * i);
      if (i + 2 < 16) v0 = hp[i + 2];
      DOT8(v1, 4 * i + 4);
    }
    // ---- pair butterfly: both lanes get the full 256-wide sums ----
    float ar = dpp_xor1_add(ar0 + ar1);
    float az = dpp_xor1_add(az0 + az1);
    float an = dpp_xor1_add(an0 + an1);

    // ---- gates (redundant on both pair lanes; no LDS exchange) ----
    float r = __builtin_amdgcn_rcpf(1.0f + __expf(-(gxr + ar + br)));
    float z = __builtin_amdgcn_rcpf(1.0f + __expf(-(gxz + az + bz)));
    float a = gxn + r * (an + bn);
    float e = __expf(-2.0f * __builtin_fabsf(a));              // in (0,1]
    float n = __builtin_copysignf((1.0f - e) * __builtin_amdgcn_rcpf(1.0f + e), a);
    float hnew = n + z * (hloc - n);
    hloc = hnew;

    if (p == 0) {
      hbuf[cur ^ 1][u >> 7][u & 127] = (_Float16)hnew;
      outb[(size_t)t * DM + u] = hnew;
    }
    __syncthreads();   // writes to buf^1 visible before next iteration reads

    gp += TG;
    gxr = nr; gxz = nz; gxn = nn;
  }
  #undef DOT8
}

extern "C" void kernel_launch(void* const* d_in, const int* in_sizes, int n_in,
                              void* d_out, int out_size, void* d_ws, size_t ws_size,
                              hipStream_t stream) {
  const float* x   = (const float*)d_in[0];
  const float* W1  = (const float*)d_in[1];
  const float* b1  = (const float*)d_in[2];
  const float* Wih = (const float*)d_in[3];
  const float* bih = (const float*)d_in[4];
  const float* Whh = (const float*)d_in[5];
  const float* bhh = (const float*)d_in[6];
  float* out = (float*)d_out;

  char* ws = (char*)d_ws;
  __half* h  = (__half*)ws;                                   // [32768,512] fp16
  size_t h_bytes = (size_t)MTOT * DI * sizeof(__half);
  h_bytes = (h_bytes + 255) & ~(size_t)255;
  __half* gxbuf = (__half*)(ws + h_bytes);                    // [32768,768] fp16

  dim3 blk(256);
  gemm_bias<false, true><<<dim3(DI / 128, MTOT / 128), blk, 0, stream>>>(
      x, W1, b1, h, MTOT, DI, DM);
  gemm_bias<true, false><<<dim3(TG / 128, MTOT / 128), blk, 0, stream>>>(
      h, Wih, bih, gxbuf, MTOT, TG, DI);
  gru_scan<<<NB, 512, 0, stream>>>(gxbuf, Whh, bhh, out);
}